// Round 1
// baseline (215.435 us; speedup 1.0000x reference)
//
#include <hip/hip_runtime.h>

// Problem constants (reference: B=64, T=512, D=1024, U=128)
#define TT 512
#define DD 1024
#define UU 128
#define MM 32768            // B*T rows
#define BK 32
#define NCHUNK 32

typedef short short8 __attribute__((ext_vector_type(8)));   // 8 bf16 (MFMA A/B frag)
typedef float f32x4 __attribute__((ext_vector_type(4)));    // MFMA C/D frag

// fp32 -> bf16 round-to-nearest-even (host-prep kernel only)
__device__ __forceinline__ unsigned short f2bf(float f) {
    union { float f; unsigned u; } v; v.f = f;
    unsigned u = v.u;
    return (unsigned short)((u + 0x7fffu + ((u >> 16) & 1u)) >> 16);
}

// 8x f32 -> short8 bf16 via v_cvt_pk_bf16_f32 (gfx950, RNE). S0 -> low16.
__device__ __forceinline__ short8 cvt8(float4 lo, float4 hi) {
    union { unsigned u[4]; short8 v; } o;
    asm("v_cvt_pk_bf16_f32 %0, %1, %2" : "=v"(o.u[0]) : "v"(lo.x), "v"(lo.y));
    asm("v_cvt_pk_bf16_f32 %0, %1, %2" : "=v"(o.u[1]) : "v"(lo.z), "v"(lo.w));
    asm("v_cvt_pk_bf16_f32 %0, %1, %2" : "=v"(o.u[2]) : "v"(hi.x), "v"(hi.y));
    asm("v_cvt_pk_bf16_f32 %0, %1, %2" : "=v"(o.u[3]) : "v"(hi.z), "v"(hi.w));
    return o.v;
}

// async global -> LDS DMA, 16 B/lane. LDS dst = wave-uniform base + lane*16.
__device__ __forceinline__ void glds16(const void* g, void* l) {
    __builtin_amdgcn_global_load_lds(
        (const __attribute__((address_space(1))) void*)g,
        (__attribute__((address_space(3))) void*)l, 16, 0, 0);
}

// ---------------------------------------------------------------------------
// Kernel 0: W[k][n] fp32 (1024x128) -> wt bf16, transposed+chunked for BK=32:
// wt[kc*4096 + n*32 + k'] = bf16(W[kc*32 + k'][n]).
// Lane order: n fastest -> coalesced 512B global reads per j.
// ---------------------------------------------------------------------------
__global__ __launch_bounds__(256) void wprep_kernel(const float* __restrict__ w,
                                                    unsigned short* __restrict__ wt) {
    int tg = blockIdx.x * 256 + threadIdx.x;   // 0..16383
    int n  = tg & 127;
    int kg = (tg >> 7) & 3;                    // 8-k group within chunk
    int kc = tg >> 9;                          // 0..31
    union { unsigned short s[8]; uint4 v; } o;
#pragma unroll
    for (int j = 0; j < 8; ++j) {
        int k = kc * 32 + kg * 8 + j;
        o.s[j] = f2bf(w[k * 128 + n]);
    }
    *(uint4*)(wt + kc * 4096 + n * 32 + kg * 8) = o.v;
}

// ---------------------------------------------------------------------------
// Kernel 1: 64(M) x 128(N) per block, 4 waves, each wave 32x64 (2x4 accs).
// BK=32, 4-buffer LDS ring, depth-3 global_load_lds prefetch pipeline with
// COUNTED vmcnt (T3+T4): wait vmcnt(8) + raw s_barrier per chunk; vmcnt only
// drains to 0 in the 2-chunk epilogue. 64 KiB LDS -> 2 blocks/CU.
//
// LDS A: 64 rows x 8 groups(16B).  slot(m,g') holds global group g = g'^(m&7).
// LDS B: 128 rows x 4 groups(16B). slot(n,g') holds global group g = g'^(n&3).
// (swizzle applied on the GLOBAL source side; glds dst stays linear)
// ---------------------------------------------------------------------------
__global__ __launch_bounds__(256, 2) void crf_energy_kernel(
    const float* __restrict__ x,               // [32768, 1024]
    const int* __restrict__ mask,              // [32768]
    const unsigned short* __restrict__ wt,     // bf16 Wt chunks [32][128][32]
    const float* __restrict__ bias,            // [128]
    const float* __restrict__ lb,              // [128]
    const float* __restrict__ rb,              // [128]
    float* __restrict__ out)                   // [32768, 128]
{
    __shared__ float lAf[4][64 * 32];           // 4 x 8 KiB (fp32 A chunk)
    __shared__ unsigned short lBs[4][128 * 32]; // 4 x 8 KiB (bf16 B chunk)

    const int tid  = threadIdx.x;
    const int w    = tid >> 6;                 // wave 0..3
    const int lane = tid & 63;
    const int q    = lane >> 4;                // 0..3
    const int r    = lane & 15;                // 0..15

    const int mh   = w >> 1;                   // 32-row half (compute role)
    const int nh   = w & 1;                    // 64-col half
    const int row0 = blockIdx.x * 64;

    // ---- staging source indices (swizzle on the GLOBAL side) ----
    // A: wave w stages rows [w*16, w*16+16), 2 instrs of 8 rows x 8 groups.
    int a_m[2], a_g[2];
#pragma unroll
    for (int j = 0; j < 2; ++j) {
        a_m[j] = w * 16 + j * 8 + (lane >> 3);
        a_g[j] = (lane & 7) ^ (a_m[j] & 7);
    }
    // B: wave w stages rows [w*32, w*32+32), 2 instrs of 16 rows x 4 groups.
    int b_n[2], b_g[2];
#pragma unroll
    for (int j = 0; j < 2; ++j) {
        b_n[j] = w * 32 + j * 16 + (lane >> 2);
        b_g[j] = (lane & 3) ^ (b_n[j] & 3);
    }

    f32x4 acc[2][4];
#pragma unroll
    for (int mt = 0; mt < 2; ++mt)
#pragma unroll
        for (int nt = 0; nt < 4; ++nt) acc[mt][nt] = (f32x4){0.f, 0.f, 0.f, 0.f};

#define STAGE(kc, bi) do {                                                      \
    _Pragma("unroll")                                                           \
    for (int j = 0; j < 2; ++j)                                                 \
        glds16(x + (size_t)(row0 + a_m[j]) * DD + (kc) * BK + a_g[j] * 4,       \
               (char*)lAf[bi] + w * 2048 + j * 1024);                           \
    _Pragma("unroll")                                                           \
    for (int j = 0; j < 2; ++j)                                                 \
        glds16(wt + (kc) * 4096 + b_n[j] * 32 + b_g[j] * 8,                     \
               (char*)lBs[bi] + w * 2048 + j * 1024);                           \
} while (0)

#define COMPUTE(bi) do {                                                        \
    const float* lA = lAf[bi];                                                  \
    const unsigned short* lB = lBs[bi];                                         \
    short8 a[2];                                                                \
    _Pragma("unroll")                                                           \
    for (int mt = 0; mt < 2; ++mt) {                                            \
        const int m  = mh * 32 + mt * 16 + r;                                   \
        const int g0 = (2 * q)     ^ (m & 7);                                   \
        const int g1 = (2 * q + 1) ^ (m & 7);                                   \
        const float4 lo = *(const float4*)(&lA[m * 32 + g0 * 4]);               \
        const float4 hi = *(const float4*)(&lA[m * 32 + g1 * 4]);               \
        a[mt] = cvt8(lo, hi);                                                   \
    }                                                                           \
    short8 b[4];                                                                \
    _Pragma("unroll")                                                           \
    for (int nt = 0; nt < 4; ++nt) {                                            \
        const int n = nh * 64 + nt * 16 + r;                                    \
        b[nt] = *(const short8*)(&lB[n * 32 + ((q ^ (n & 3)) * 8)]);            \
    }                                                                           \
    _Pragma("unroll")                                                           \
    for (int mt = 0; mt < 2; ++mt)                                              \
        _Pragma("unroll")                                                       \
        for (int nt = 0; nt < 4; ++nt)                                          \
            acc[mt][nt] = __builtin_amdgcn_mfma_f32_16x16x32_bf16(              \
                a[mt], b[nt], acc[mt][nt], 0, 0, 0);                            \
} while (0)

#define WAITBAR(vstr) do {                                                      \
    asm volatile("s_waitcnt vmcnt(" vstr ")" ::: "memory");                     \
    __builtin_amdgcn_s_barrier();                                               \
    __builtin_amdgcn_sched_barrier(0);                                          \
} while (0)

    // ---- prologue: stage chunks 0,1,2 (12 loads/wave in flight)
    STAGE(0, 0);
    STAGE(1, 1);
    STAGE(2, 2);

    // ---- main loop: chunk k ready (vmcnt<=8), k+1/k+2 in flight, issue k+3
    for (int kc = 0; kc < NCHUNK - 3; ++kc) {      // kc = 0..28
        WAITBAR("8");
        STAGE(kc + 3, (kc + 3) & 3);
        COMPUTE(kc & 3);
    }
    // ---- epilogue chunks 29,30,31: drain 8 -> 4 -> 0
    WAITBAR("8");
    COMPUTE(1);                                    // kc=29
    WAITBAR("4");
    COMPUTE(2);                                    // kc=30
    WAITBAR("0");
    COMPUTE(3);                                    // kc=31

    // ---- epilogue: bias + boundary masks.  C/D: col=lane&15 (N), row=q*4+reg (M).
#pragma unroll
    for (int mt = 0; mt < 2; ++mt) {
#pragma unroll
        for (int reg = 0; reg < 4; ++reg) {
            const int m = row0 + mh * 32 + mt * 16 + q * 4 + reg;
            const int t = m & (TT - 1);
            const int cur  = mask[m];
            const int prev = (t != 0)      ? mask[m - 1] : 0;
            const int nxt  = (t != TT - 1) ? mask[m + 1] : 0;
            const float sm = (cur > prev) ? 1.f : 0.f;   // start_mask
            const float em = (nxt > cur)  ? 1.f : 0.f;   // end_mask
#pragma unroll
            for (int nt = 0; nt < 4; ++nt) {
                const int n = nh * 64 + nt * 16 + r;
                float e = acc[mt][nt][reg] + bias[n] + sm * lb[n] + em * rb[n];
                out[(size_t)m * UU + n] = e;
            }
        }
    }
#undef STAGE
#undef COMPUTE
#undef WAITBAR
}

extern "C" void kernel_launch(void* const* d_in, const int* in_sizes, int n_in,
                              void* d_out, int out_size, void* d_ws, size_t ws_size,
                              hipStream_t stream) {
    const float* x    = (const float*)d_in[0];
    const int*   mask = (const int*)d_in[1];
    const float* w    = (const float*)d_in[2];
    const float* bias = (const float*)d_in[3];
    const float* lb   = (const float*)d_in[4];
    const float* rb   = (const float*)d_in[5];
    float* out = (float*)d_out;
    unsigned short* wt = (unsigned short*)d_ws;   // 256 KiB bf16 Wt

    wprep_kernel<<<64, 256, 0, stream>>>(w, wt);
    // 512 blocks * 64 KB LDS = exactly 2 resident blocks/CU, 4-buffer ring
    crf_energy_kernel<<<512, 256, 0, stream>>>(x, mask, wt, bias, lb, rb, out);
}